// Round 17
// baseline (58.617 us; speedup 1.0000x reference)
//
#include <hip/hip_runtime.h>

#define TSTEPS 128
#define NBATCH 2048
#define DIN    32
#define INV_PI 0.31830988618379067f

// ---- DPP helpers ----
template <int CTRL>
__device__ __forceinline__ float qperm(float v) {   // quad_perm, all lanes valid
    return __int_as_float(
        __builtin_amdgcn_mov_dpp(__float_as_int(v), CTRL, 0xF, 0xF, true));
}
template <int CTRL>
__device__ __forceinline__ float dpp_z(float v) {   // row shift, invalid -> 0
    return __int_as_float(__builtin_amdgcn_update_dpp(
        0, __float_as_int(v), CTRL, 0xF, 0xF, true));
}
template <int CTRL>
__device__ __forceinline__ float dpp_k(float oldv, float v) { // invalid -> keep old
    return __int_as_float(__builtin_amdgcn_update_dpp(
        __float_as_int(oldv), __float_as_int(v), CTRL, 0xF, 0xF, false));
}
// ctrl: quad_perm 0x00-0xFF; row_shl:N = 0x100+N; row_shr:N = 0x110+N.
// 0x1B = quad XOR-3.

// ===================== Fused v3: projection + recurrence =====================
// 512 blocks x 256 thr. Block owns batches B0..B0+3, all 128 timesteps.
// Phase 1 (all 4 waves, 2 passes x 256 rows): x -> Xt (coalesced, 33-pad) ->
//   1 row/thread dot products -> Xls[row*16 + g2*4+i] (g2: 0=f,1=o,2=i,3=u),
//   i.e. exactly the [t][bl*16+r] layout R14's recurrence reads.
// Phase 2 (wave 0): R14 recurrence verbatim on Xls. Waves 1-3 park at barrier.
// Epilogue: all 256 threads flush Ols coalesced.
extern "C" __global__ void __launch_bounds__(256)
qlstm_f3(const float* __restrict__ x,
         const float* __restrict__ Wf, const float* __restrict__ bfp,
         const float* __restrict__ Wi, const float* __restrict__ bip,
         const float* __restrict__ Wu, const float* __restrict__ bup,
         const float* __restrict__ Wo, const float* __restrict__ bop,
         float* __restrict__ out)
{
    __shared__ float4 WL[16 * 8];          // 2 KB
    __shared__ float  bias[16];
    __shared__ float  Xt[256 * 33];        // 33.8 KB staging tile
    __shared__ float  Xls[TSTEPS * 64];    // 32 KB: [t][bl*16 + r]
    __shared__ float  Ols[TSTEPS * 16];    // 8 KB:  [t][bl*4 + i]

    const int tid = threadIdx.x;
    const int B0  = blockIdx.x * 4;

    // ---- stage weights (pre-scaled 1/pi), g2-major ----
    float* WLf = (float*)WL;
    for (int idx = tid; idx < 512; idx += 256) {
        int rr = idx >> 5, k = idx & 31;             // rr = g2*4+i
        int g2 = rr >> 2, i = rr & 3;
        const float* W = (g2 == 0) ? Wf : (g2 == 1) ? Wo : (g2 == 2) ? Wi : Wu;
        WLf[rr * 32 + k] = W[i * 36 + k] * INV_PI;
    }
    if (tid < 16) {
        int g2 = tid >> 2, i = tid & 3;
        const float* bp = (g2 == 0) ? bfp : (g2 == 1) ? bop : (g2 == 2) ? bip : bup;
        bias[tid] = bp[i] * INV_PI;
    }

    // ---- phase 1: two passes of 256 rows (row = t*4 + b, t-half per pass) ----
    const float4* xv = reinterpret_cast<const float4*>(x);
    float4* Xls4 = reinterpret_cast<float4*>(Xls);
    for (int pass = 0; pass < 2; ++pass) {
        __syncthreads();   // protect Xt reuse (and WL on first iteration)
        // coalesced stage: 8 rounds x 256 lanes x float4 (8 rows/wave/round)
#pragma unroll
        for (int rnd = 0; rnd < 8; ++rnd) {
            int f4 = rnd * 256 + tid;                // 0..2047
            int lr = f4 >> 3, el = f4 & 7;           // local row, element
            int t  = pass * 64 + (lr >> 2), b = lr & 3;
            float4 v = xv[((size_t)t * NBATCH + (size_t)(B0 + b)) * 8 + el];
            float* dst = &Xt[lr * 33 + el * 4];
            dst[0] = v.x; dst[1] = v.y; dst[2] = v.z; dst[3] = v.w;
        }
        __syncthreads();
        // compute 1 row/thread (R14-proven shape)
        float xrow[32];
#pragma unroll
        for (int e = 0; e < 32; ++e) xrow[e] = Xt[tid * 33 + e];
        float acc[16];
#pragma unroll
        for (int rr = 0; rr < 16; ++rr) {
            float s = bias[rr];
#pragma unroll
            for (int k = 0; k < 8; ++k) {
                float4 w = WL[rr * 8 + k];           // uniform -> broadcast
                s = fmaf(xrow[k * 4 + 0], w.x, s);
                s = fmaf(xrow[k * 4 + 1], w.y, s);
                s = fmaf(xrow[k * 4 + 2], w.z, s);
                s = fmaf(xrow[k * 4 + 3], w.w, s);
            }
            acc[rr] = s;
        }
        // write into recurrence layout: Xls float-idx = grow*16 + rr,
        // grow = pass*256 + tid  (= t*4+b  ->  t*64 + b*16 + rr)
        const int xb4 = (pass * 256 + tid) * 4;      // float4 units
#pragma unroll
        for (int g2 = 0; g2 < 4; ++g2)
            Xls4[xb4 + g2] = make_float4(acc[g2 * 4 + 0], acc[g2 * 4 + 1],
                                         acc[g2 * 4 + 2], acc[g2 * 4 + 3]);
    }
    __syncthreads();   // Xls complete

    // ---- phase 2: wave 0 recurrence (R14 verbatim) ----
    if (tid < 64) {
        const int l  = tid;
        const int bl = l >> 4;
        const int r  = l & 15;
        const int g  = r >> 2;                // 0=f,1=o,2=i,3=u
        const int i  = r & 3;
        const int bg = B0 + bl;
        const bool m1 = (i >= 1), m2 = (i >= 2);

        const float* Wg = (g == 0) ? Wf : (g == 1) ? Wo : (g == 2) ? Wi : Wu;
        float wh0 = Wg[i * 36 + 32 + (i ^ 0)] * INV_PI;
        float wh1 = Wg[i * 36 + 32 + (i ^ 1)] * INV_PI;
        float wh2 = Wg[i * 36 + 32 + (i ^ 2)] * INV_PI;
        float wh3 = Wg[i * 36 + 32 + (i ^ 3)] * INV_PI;

        const bool isU = (g == 3);
        const float c0 = isU ? 0.0008346f : 0.499971f;
        const float c1 = isU ? 1.036967f  : 0.250882f;
        const float c2 = isU ? -0.175884f : -0.004115f;
        const float c3 = isU ? -0.099350f : -0.015724f;
        const float T0 = 0.99827f,  T1 = -0.313542f, T2 = 0.0915168f,
                    T3 = -0.0160296f, T4 = 0.0011677f;

        float ha = 0.f, hx1 = 0.f, hx2 = 0.f, hx3 = 0.f, cst = 0.f;

        auto qstep = [&](float xp, int t) {
            float A  = fmaf(wh0, ha,  xp);
            float Bt = fmaf(wh1, hx1, wh2 * hx2);
            float p  = fmaf(wh3, hx3, A) + Bt;
            float fr = __builtin_amdgcn_fractf(p);
            float cs = __builtin_amdgcn_cosf(fr);
            float q  = fmaf(0.5f, cs, 0.5f);
            float s1 = qperm<0x90>(q);  q *= m1 ? s1 : 1.0f;
            float s2 = qperm<0x44>(q);  q *= m2 ? s2 : 1.0f;
            float y  = fmaf(fmaf(fmaf(c3, q, c2), q, c1), q, c0);
            float t1 = dpp_z<0x104>(y);          // f<-sig_o, i<-tanh_u
            float m_ = y * t1;                   // i-lanes: sig_i * tanh_u
            float t2 = dpp_z<0x108>(m_);         // f-lanes <- i*u
            cst = fmaf(y, cst, t2);              // f-lanes: f*c + i*u
            float tt = cst * cst;
            float gg = fmaf(fmaf(fmaf(fmaf(T4, tt, T3), tt, T2), tt, T1), tt, T0);
            float th = cst * gg;
            float hn = t1 * th;                  // o * tanh(c) at f-lanes
            if (r < 4) Ols[t * 16 + bl * 4 + r] = hn;
            float d1 = dpp_k<0x114>(hn, hn);     // lanes 4..7  <- 0..3
            float d2 = dpp_k<0x118>(d1, d1);     // lanes 8..15 <- 0..7
            ha  = d2;
            hx1 = qperm<0xB1>(d2);
            hx2 = qperm<0x4E>(d2);
            hx3 = qperm<0x1B>(d2);
        };

        float xr[4];
#pragma unroll
        for (int k = 0; k < 4; ++k) xr[k] = Xls[k * 64 + l];

        for (int t0 = 0; t0 < TSTEPS; t0 += 4) {
#pragma unroll
            for (int k = 0; k < 4; ++k) {
                const int t = t0 + k;
                float xp = xr[k];
                int tn = t + 4;  if (tn > TSTEPS - 1) tn = TSTEPS - 1;
                xr[k] = Xls[tn * 64 + l];
                qstep(xp, t);
            }
        }

        const size_t off = (size_t)TSTEPS * NBATCH * 4;
        if (r < 4) {
            out[off + (size_t)bg * 4 + r] = ha;                       // final hx
            out[off + (size_t)NBATCH * 4 + (size_t)bg * 4 + r] = cst; // final cx
        }
    }
    __syncthreads();   // Ols complete

    // ---- flush outputs: 2 float4 per thread, coalesced ----
    float4* outv = reinterpret_cast<float4*>(out);
    const float4* Ols4 = reinterpret_cast<const float4*>(Ols);
#pragma unroll
    for (int m = 0; m < 2; ++m) {
        int f4 = m * 256 + tid;              // 0..511
        int t = f4 >> 2, q4 = f4 & 3;
        outv[(size_t)t * NBATCH + B0 + q4] = Ols4[f4];
    }
}

extern "C" void kernel_launch(void* const* d_in, const int* in_sizes, int n_in,
                              void* d_out, int out_size, void* d_ws, size_t ws_size,
                              hipStream_t stream) {
    (void)in_sizes; (void)n_in; (void)out_size; (void)d_ws; (void)ws_size;
    const float* x  = (const float*)d_in[0];
    const float* Wf = (const float*)d_in[1];
    const float* bf = (const float*)d_in[2];
    // d_in[3] = pf: RZ phases drop out of the measurement -> unused
    const float* Wi = (const float*)d_in[4];
    const float* bi = (const float*)d_in[5];
    const float* Wu = (const float*)d_in[7];
    const float* bu = (const float*)d_in[8];
    const float* Wo = (const float*)d_in[10];
    const float* bo = (const float*)d_in[11];
    float* out = (float*)d_out;

    hipLaunchKernelGGL(qlstm_f3, dim3(NBATCH / 4), dim3(256), 0, stream,
                       x, Wf, bf, Wi, bi, Wu, bu, Wo, bo, out);
}

// Round 18
// 34.650 us; speedup vs baseline: 1.6917x; 1.6917x over previous
//
#include <hip/hip_runtime.h>
#include <hip/hip_fp16.h>

#define TSTEPS 128
#define NBATCH 2048
#define DIN    32
#define NROWS  (TSTEPS * NBATCH)
#define INV_PI 0.31830988618379067f

// ---- DPP helpers ----
template <int CTRL>
__device__ __forceinline__ float qperm(float v) {   // quad_perm, all lanes valid
    return __int_as_float(
        __builtin_amdgcn_mov_dpp(__float_as_int(v), CTRL, 0xF, 0xF, true));
}
template <int CTRL>
__device__ __forceinline__ float dpp_z(float v) {   // row shift, invalid -> 0
    return __int_as_float(__builtin_amdgcn_update_dpp(
        0, __float_as_int(v), CTRL, 0xF, 0xF, true));
}
template <int CTRL>
__device__ __forceinline__ float dpp_k(float oldv, float v) { // invalid -> keep old
    return __int_as_float(__builtin_amdgcn_update_dpp(
        __float_as_int(oldv), __float_as_int(v), CTRL, 0xF, 0xF, false));
}
// ctrl: quad_perm 0x00-0xFF; row_shl:N = 0x100+N; row_shr:N = 0x110+N.
// 0x1B = quad XOR-3.

// ============ Kernel A v6: x-projection, coalesced, fp16 ws ============
// ws (half) [row*16 + rr] = (1/pi)*(b_g[i] + x[row,:] . W_g[i,0:32]),
// rr = g2*4+i, gate order g2: 0=f,1=o,2=i,3=u.  row = t*NBATCH + b.
// 1024 blocks x 256 thr, 1 row/thread (R14's proven shape). Loads staged
// coalesced via padded LDS tile; stores are 32 B contiguous per thread.
extern "C" __global__ void __launch_bounds__(256)
xproj_kernel(const float* __restrict__ x,
             const float* __restrict__ Wf, const float* __restrict__ bfp,
             const float* __restrict__ Wi, const float* __restrict__ bip,
             const float* __restrict__ Wu, const float* __restrict__ bup,
             const float* __restrict__ Wo, const float* __restrict__ bop,
             float* __restrict__ ws)
{
    __shared__ float4 WL[16 * 8];          // 2 KB
    __shared__ float  bias[16];
    __shared__ float  Xt[256 * 33];        // 33.8 KB padded x-tile

    const int tid = threadIdx.x;
    float* WLf = (float*)WL;
    for (int idx = tid; idx < 512; idx += 256) {
        int rr = idx >> 5, k = idx & 31;             // rr = g2*4+i
        int g2 = rr >> 2, i = rr & 3;
        const float* W = (g2 == 0) ? Wf : (g2 == 1) ? Wo : (g2 == 2) ? Wi : Wu;
        WLf[rr * 32 + k] = W[i * 36 + k] * INV_PI;
    }
    if (tid < 16) {
        int g2 = tid >> 2, i = tid & 3;
        const float* bp = (g2 == 0) ? bfp : (g2 == 1) ? bop : (g2 == 2) ? bip : bup;
        bias[tid] = bp[i] * INV_PI;
    }

    // ---- stage 256 rows coalesced: 8 rounds x 256 lanes x float4 ----
    const int rowbase = blockIdx.x * 256;
    const float4* xv = reinterpret_cast<const float4*>(x) + (size_t)rowbase * 8;
#pragma unroll
    for (int rnd = 0; rnd < 8; ++rnd) {
        int f4 = rnd * 256 + tid;                    // 0..2047, lane-contiguous
        float4 v = xv[f4];
        int row = f4 >> 3, el = f4 & 7;
        float* dst = &Xt[row * 33 + el * 4];
        dst[0] = v.x; dst[1] = v.y; dst[2] = v.z; dst[3] = v.w;
    }
    __syncthreads();

    // ---- compute 1 row/thread from LDS (conflict-free b32 reads) ----
    float xrow[32];
#pragma unroll
    for (int e = 0; e < 32; ++e) xrow[e] = Xt[tid * 33 + e];

    float acc[16];
#pragma unroll
    for (int rr = 0; rr < 16; ++rr) {
        float s = bias[rr];
#pragma unroll
        for (int k = 0; k < 8; ++k) {
            float4 w = WL[rr * 8 + k];               // uniform -> broadcast
            s = fmaf(xrow[k * 4 + 0], w.x, s);
            s = fmaf(xrow[k * 4 + 1], w.y, s);
            s = fmaf(xrow[k * 4 + 2], w.z, s);
            s = fmaf(xrow[k * 4 + 3], w.w, s);
        }
        acc[rr] = s;
    }

    // ---- fp16 pack + 32 B-contiguous store per thread ----
    __half2 hh[8];
#pragma unroll
    for (int j = 0; j < 8; ++j)
        hh[j] = __floats2half2_rn(acc[2 * j], acc[2 * j + 1]);
    float4* wsh4 = reinterpret_cast<float4*>(ws);
    const int row = rowbase + tid;
    wsh4[row * 2 + 0] = *reinterpret_cast<float4*>(&hh[0]);
    wsh4[row * 2 + 1] = *reinterpret_cast<float4*>(&hh[4]);
}

// ============== Kernel B: serial recurrence (R14 chain, fp16 staging) ==============
// 16 lanes per batch: lane = bl*16 + r, r = g*4+i (g: 0=f,1=o,2=i,3=u).
// 4 batches/wave, 1 wave/block, 512 blocks.
// Staging reads half the bytes (1 coalesced round); chain is byte-identical R14.
extern "C" __global__ void __launch_bounds__(64)
recur_kernel(const float* __restrict__ ws,
             const float* __restrict__ Wf, const float* __restrict__ Wi,
             const float* __restrict__ Wu, const float* __restrict__ Wo,
             float* __restrict__ out)
{
    __shared__ float Xls[TSTEPS * 64];    // 32 KB fp32: [t][bl*16 + r]
    __shared__ float Ols[TSTEPS * 16];    // 8 KB:  [t][bl*4 + i]

    const int l  = threadIdx.x;
    const int bl = l >> 4;
    const int r  = l & 15;
    const int g  = r >> 2;                // 0=f,1=o,2=i,3=u
    const int i  = r & 3;
    const int B0g = blockIdx.x * 4;
    const int bg  = B0g + bl;
    const bool m1 = (i >= 1), m2 = (i >= 2);

    // ---- stage X slice: 1 round x 16 float4 (each = 8 halves), cvt off-chain ----
    const float4* wsh4 = reinterpret_cast<const float4*>(ws);
    float4* Xls4 = reinterpret_cast<float4*>(Xls);
    {
        float4 v[16];
#pragma unroll
        for (int m = 0; m < 16; ++m) {
            int f4 = m * 64 + l;                  // 0..1023
            int lr = f4 >> 1, hf = f4 & 1;        // local row, half-of-row
            int t = lr >> 2, b2 = lr & 3;
            v[m] = wsh4[(size_t)t * (NBATCH * 2) + (size_t)(B0g + b2) * 2 + hf];
        }
#pragma unroll
        for (int m = 0; m < 16; ++m) {
            int f4 = m * 64 + l;
            const __half2* hp = reinterpret_cast<const __half2*>(&v[m]);
            float2 f0 = __half22float2(hp[0]);
            float2 f1 = __half22float2(hp[1]);
            float2 f2 = __half22float2(hp[2]);
            float2 f3 = __half22float2(hp[3]);
            Xls4[f4 * 2 + 0] = make_float4(f0.x, f0.y, f1.x, f1.y);
            Xls4[f4 * 2 + 1] = make_float4(f2.x, f2.y, f3.x, f3.y);
        }
    }

    const float* Wg = (g == 0) ? Wf : (g == 1) ? Wo : (g == 2) ? Wi : Wu;
    float wh0 = Wg[i * 36 + 32 + (i ^ 0)] * INV_PI;
    float wh1 = Wg[i * 36 + 32 + (i ^ 1)] * INV_PI;
    float wh2 = Wg[i * 36 + 32 + (i ^ 2)] * INV_PI;
    float wh3 = Wg[i * 36 + 32 + (i ^ 3)] * INV_PI;

    // gate activation: deg-3 poly on q in [0,1]. g!=3: sigmoid; g==3: tanh.
    const bool isU = (g == 3);
    const float c0 = isU ? 0.0008346f : 0.499971f;
    const float c1 = isU ? 1.036967f  : 0.250882f;
    const float c2 = isU ? -0.175884f : -0.004115f;
    const float c3 = isU ? -0.099350f : -0.015724f;
    // tanh(c) for |c|<=2.08: c*P(c^2), deg-4
    const float T0 = 0.99827f,  T1 = -0.313542f, T2 = 0.0915168f,
                T3 = -0.0160296f, T4 = 0.0011677f;

    float ha = 0.f, hx1 = 0.f, hx2 = 0.f, hx3 = 0.f, cst = 0.f;

    __syncthreads();   // LDS X visible across lanes

    auto qstep = [&](float xp, int t) {
        float A  = fmaf(wh0, ha,  xp);
        float Bt = fmaf(wh1, hx1, wh2 * hx2);
        float p  = fmaf(wh3, hx3, A) + Bt;
        float fr = __builtin_amdgcn_fractf(p);
        float cs = __builtin_amdgcn_cosf(fr);
        float q  = fmaf(0.5f, cs, 0.5f);
        float s1 = qperm<0x90>(q);  q *= m1 ? s1 : 1.0f;
        float s2 = qperm<0x44>(q);  q *= m2 ? s2 : 1.0f;
        float y  = fmaf(fmaf(fmaf(c3, q, c2), q, c1), q, c0);
        float t1 = dpp_z<0x104>(y);          // f<-sig_o, i<-tanh_u
        float m_ = y * t1;                   // i-lanes: sig_i * tanh_u
        float t2 = dpp_z<0x108>(m_);         // f-lanes <- i*u
        cst = fmaf(y, cst, t2);              // f-lanes: f*c + i*u
        float tt = cst * cst;
        float gg = fmaf(fmaf(fmaf(fmaf(T4, tt, T3), tt, T2), tt, T1), tt, T0);
        float th = cst * gg;
        float hn = t1 * th;                  // o * tanh(c) at f-lanes
        if (r < 4) Ols[t * 16 + bl * 4 + r] = hn;
        float d1 = dpp_k<0x114>(hn, hn);     // lanes 4..7  <- 0..3
        float d2 = dpp_k<0x118>(d1, d1);     // lanes 8..15 <- 0..7
        ha  = d2;
        hx1 = qperm<0xB1>(d2);
        hx2 = qperm<0x4E>(d2);
        hx3 = qperm<0x1B>(d2);
    };

    // 4-deep LDS->reg prefetch ring
    float xr[4];
#pragma unroll
    for (int k = 0; k < 4; ++k) xr[k] = Xls[k * 64 + l];

    for (int t0 = 0; t0 < TSTEPS; t0 += 4) {
#pragma unroll
        for (int k = 0; k < 4; ++k) {
            const int t = t0 + k;
            float xp = xr[k];
            int tn = t + 4;  if (tn > TSTEPS - 1) tn = TSTEPS - 1;
            xr[k] = Xls[tn * 64 + l];
            qstep(xp, t);
        }
    }

    __syncthreads();   // Ols complete

    // ---- flush outputs: 8 float4 per lane, coalesced ----
    float4* outv = reinterpret_cast<float4*>(out);
    const float4* Ols4 = reinterpret_cast<const float4*>(Ols);
#pragma unroll
    for (int m = 0; m < 8; ++m) {
        int f4 = m * 64 + l;                 // 0..511
        int t = f4 >> 2, q4 = f4 & 3;
        outv[(size_t)t * (NBATCH) + B0g + q4] = Ols4[f4];
    }

    const size_t off = (size_t)TSTEPS * NBATCH * 4;
    if (r < 4) {
        out[off + (size_t)bg * 4 + r] = ha;                       // final hx
        out[off + (size_t)NBATCH * 4 + (size_t)bg * 4 + r] = cst; // final cx
    }
}

extern "C" void kernel_launch(void* const* d_in, const int* in_sizes, int n_in,
                              void* d_out, int out_size, void* d_ws, size_t ws_size,
                              hipStream_t stream) {
    (void)in_sizes; (void)n_in; (void)out_size; (void)ws_size;
    const float* x  = (const float*)d_in[0];
    const float* Wf = (const float*)d_in[1];
    const float* bf = (const float*)d_in[2];
    // d_in[3] = pf: RZ phases drop out of the measurement -> unused
    const float* Wi = (const float*)d_in[4];
    const float* bi = (const float*)d_in[5];
    const float* Wu = (const float*)d_in[7];
    const float* bu = (const float*)d_in[8];
    const float* Wo = (const float*)d_in[10];
    const float* bo = (const float*)d_in[11];
    float* out = (float*)d_out;

    float* ws = (float*)d_ws;   // 8.4 MB (fp16) needed; harness ws is larger
    hipLaunchKernelGGL(xproj_kernel, dim3(NROWS / 256), dim3(256), 0, stream,
                       x, Wf, bf, Wi, bi, Wu, bu, Wo, bo, ws);
    hipLaunchKernelGGL(recur_kernel, dim3(NBATCH / 4), dim3(64), 0, stream,
                       ws, Wf, Wi, Wu, Wo, out);
}